// Round 4
// baseline (553.605 us; speedup 1.0000x reference)
//
#include <hip/hip_runtime.h>
#include <hip/hip_cooperative_groups.h>

namespace cg = cooperative_groups;

#define EPS_BN 1e-5f

typedef float f32x4 __attribute__((ext_vector_type(4)));

// Padded plane: logical rows -1..32 at index r+1 (34 rows), cols -1..34 at
// index c+1 (36 cols). float4 read of 6-wide strip starts 16B-aligned.
#define PROWS 34
#define PCOLS 36
#define PS (PROWS * PCOLS)   // 1224

// ---------------------------------------------------------------------------
// helpers
// ---------------------------------------------------------------------------
__device__ __forceinline__ void bn_prologue(
    const float* __restrict__ in_stats, const float* __restrict__ gamma,
    const float* __restrict__ beta, const float* __restrict__ wgt_co, // (64,9)
    float* s_sc, float* s_sh, float* s_corr, int tid, int ci_lo, int ci_hi)
{
    if (tid < 64) {
        float s    = in_stats[tid];
        float ss   = in_stats[64 + tid];
        float mean = s * (1.0f / 4096.0f);
        float var  = fmaxf(ss * (1.0f / 4096.0f) - mean * mean, 0.0f);
        float g    = gamma[tid] * rsqrtf(var + EPS_BN);
        float sh   = beta[tid] - mean * g;
        s_sc[tid] = g;
        s_sh[tid] = sh;
        // pad-tap correction: zero-pad input produces relu(sh) after BN+ReLU
        float rl = (tid >= ci_lo && tid < ci_hi) ? fmaxf(sh, 0.0f) : 0.0f;
        const float* wp = wgt_co + tid * 9;
        float w0=wp[0], w1=wp[1], w2=wp[2], w3=wp[3],
              w5=wp[5], w6=wp[6], w7=wp[7], w8=wp[8];
        float pT  = rl * (w0 + w1 + w2);
        float pB  = rl * (w6 + w7 + w8);
        float pL  = rl * (w0 + w3 + w6);
        float pR  = rl * (w2 + w5 + w8);
        float pTL = rl * w0, pTR = rl * w2, pBL = rl * w6, pBR = rl * w8;
        #pragma unroll
        for (int off = 32; off; off >>= 1) {
            pT  += __shfl_down(pT,  off); pB  += __shfl_down(pB,  off);
            pL  += __shfl_down(pL,  off); pR  += __shfl_down(pR,  off);
            pTL += __shfl_down(pTL, off); pTR += __shfl_down(pTR, off);
            pBL += __shfl_down(pBL, off); pBR += __shfl_down(pBR, off);
        }
        if (tid == 0) {
            s_corr[0]=pT; s_corr[1]=pB; s_corr[2]=pL; s_corr[3]=pR;
            s_corr[4]=pTL; s_corr[5]=pTR; s_corr[6]=pBL; s_corr[7]=pBR;
        }
    }
    __syncthreads();
}

template<int CIN, bool BN_IN>
__device__ __forceinline__ void conv_core(
    const float* __restrict__ inp,    // base of CIN padded planes (image n)
    const float* __restrict__ wgt9,   // CIN rows of 9 weights (this co)
    const float* s_sc, const float* s_sh,
    int r, int c4, float& u0, float& u1, float& u2, float& u3)
{
    const float* ip = inp + r * PCOLS + c4;   // padded (r-1, c4-1)
    float acc0=0.f, acc1=0.f, acc2=0.f, acc3=0.f;
    #pragma unroll 4
    for (int ci = 0; ci < CIN; ++ci) {
        const float* p  = ip + ci * PS;
        const float* wp = wgt9 + ci * 9;      // block-uniform -> s_load
        float sc = 0.f, sh = 0.f;
        if (BN_IN) { sc = s_sc[ci]; sh = s_sh[ci]; }
        #pragma unroll
        for (int dr = 0; dr < 3; ++dr) {
            float4 a = *(const float4*)(p + dr * PCOLS);
            float2 b = *(const float2*)(p + dr * PCOLS + 4);
            float h0,h1,h2,h3,h4,h5;
            if (BN_IN) {
                h0 = fmaxf(fmaf(sc, a.x, sh), 0.f);
                h1 = fmaxf(fmaf(sc, a.y, sh), 0.f);
                h2 = fmaxf(fmaf(sc, a.z, sh), 0.f);
                h3 = fmaxf(fmaf(sc, a.w, sh), 0.f);
                h4 = fmaxf(fmaf(sc, b.x, sh), 0.f);
                h5 = fmaxf(fmaf(sc, b.y, sh), 0.f);
            } else {
                h0 = a.x; h1 = a.y; h2 = a.z; h3 = a.w; h4 = b.x; h5 = b.y;
            }
            float wa = wp[dr*3+0], wb = wp[dr*3+1], wc = wp[dr*3+2];
            acc0 = fmaf(wa, h0, fmaf(wb, h1, fmaf(wc, h2, acc0)));
            acc1 = fmaf(wa, h1, fmaf(wb, h2, fmaf(wc, h3, acc1)));
            acc2 = fmaf(wa, h2, fmaf(wb, h3, fmaf(wc, h4, acc2)));
            acc3 = fmaf(wa, h3, fmaf(wb, h4, fmaf(wc, h5, acc3)));
        }
    }
    u0 = acc0; u1 = acc1; u2 = acc2; u3 = acc3;
}

__device__ __forceinline__ void apply_corr(
    const float* s_corr, int r, int c4,
    float& u0, float& u1, float& u2, float& u3)
{
    float corr = (r == 0 ? s_corr[0] : 0.f) + (r == 31 ? s_corr[1] : 0.f);
    u0 -= corr; u1 -= corr; u2 -= corr; u3 -= corr;
    if (c4 == 0) {
        u0 -= s_corr[2];
        if (r == 0)  u0 += s_corr[4];
        if (r == 31) u0 += s_corr[6];
    }
    if (c4 == 28) {
        u3 -= s_corr[3];
        if (r == 0)  u3 += s_corr[5];
        if (r == 31) u3 += s_corr[7];
    }
}

__device__ __forceinline__ void write_padded(
    float* __restrict__ plane, int r, int c4, int tid,
    float u0, float u1, float u2, float u3)
{
    float* op = plane + (r + 1) * PCOLS + (c4 + 1);
    op[0]=u0; op[1]=u1; op[2]=u2; op[3]=u3;
    if (tid < 136) {                 // zero the border (136 elements)
        int e;
        if      (tid < 36)  e = tid;                         // top row
        else if (tid < 72)  e = 33 * PCOLS + (tid - 36);     // bottom row
        else if (tid < 104) e = (tid - 72 + 1) * PCOLS;      // left col
        else                e = (tid - 104 + 1) * PCOLS + 35;// right col
        plane[e] = 0.f;
    }
}

__device__ __forceinline__ void stats_acc(
    float* __restrict__ lstats, int co, int tid,
    float u0, float u1, float u2, float u3)
{
    float s  = u0 + u1 + u2 + u3;
    float ss = u0*u0 + u1*u1 + u2*u2 + u3*u3;
    #pragma unroll
    for (int off = 32; off; off >>= 1) {
        s  += __shfl_down(s,  off);
        ss += __shfl_down(ss, off);
    }
    if ((tid & 63) == 0) {
        atomicAdd(&lstats[co],      s);
        atomicAdd(&lstats[64 + co], ss);
    }
}

// ---------------------------------------------------------------------------
// One cooperative kernel: pad+zero, 5 conv+BN(+stats) layers, regressor.
// 256 blocks x 256 threads; grid.sync() between layers (replaces 7 kernel
// boundaries). Conv biases for BN-followed layers are skipped (BN cancels
// them exactly). Regressor is ci-split x4 over 192 blocks, atomicAdd into
// pre-zeroed xf.
// ---------------------------------------------------------------------------
__global__ __launch_bounds__(256) void fused_conv(
    const float* __restrict__ x,       // (4,12,32,32)
    const float* __restrict__ conv0w,  // (64,12,3,3)
    const float* __restrict__ convw,   // (4,64,64,3,3)
    const float* __restrict__ gammas,  // (5,64)
    const float* __restrict__ betas,   // (5,64)
    const float* __restrict__ regw,    // (12,64,3,3)
    const float* __restrict__ regb,    // (12)
    float* __restrict__ bufX,          // (48,PS)
    float* __restrict__ bufA,          // (256,PS)
    float* __restrict__ bufB,          // (256,PS)
    float* __restrict__ stats,         // (5,2,64)
    float* __restrict__ xf)            // (4,12,1024)
{
    cg::grid_group grid = cg::this_grid();
    __shared__ float s_sc[64];
    __shared__ float s_sh[64];
    __shared__ float s_corr[8];

    const int tid = threadIdx.x;
    const int b   = blockIdx.x;
    const int r   = tid >> 3;
    const int c4  = (tid & 7) << 2;

    // ---- phase 0: pad x, zero xf, zero stats ----
    if (b < 48) {
        const float* xp = x + (b << 10);
        float* o = bufX + b * PS;
        for (int e = tid; e < PS; e += 256) {
            int rr = e / PCOLS, cc = e - rr * PCOLS;
            int ir = rr - 1, ic = cc - 1;
            float v = ((unsigned)ir < 32u && (unsigned)ic < 32u)
                        ? xp[(ir << 5) + ic] : 0.f;
            o[e] = v;
        }
    } else if (b < 96) {
        f32x4 z = {0.f, 0.f, 0.f, 0.f};
        ((f32x4*)(xf + ((b - 48) << 10)))[tid] = z;
    } else if (b == 96) {
        for (int e = tid; e < 640; e += 256) stats[e] = 0.f;
    }
    grid.sync();

    const int n  = b >> 6;
    const int co = b & 63;

    // ---- layer 0: 12 -> 64, raw input (true zero pads), stats0 ----
    {
        float u0,u1,u2,u3;
        conv_core<12,false>(bufX + n * 12 * PS, conv0w + co * 108,
                            s_sc, s_sh, r, c4, u0,u1,u2,u3);
        write_padded(bufA + (n * 64 + co) * PS, r, c4, tid, u0,u1,u2,u3);
        stats_acc(stats, co, tid, u0,u1,u2,u3);
    }
    grid.sync();

    // ---- layers 1..4: 64 -> 64, BN(prev)+ReLU fused into input read ----
    #pragma unroll 1
    for (int L = 1; L <= 4; ++L) {
        const float* bin  = (L & 1) ? bufA : bufB;
        float*       bout = (L & 1) ? bufB : bufA;
        const float* w    = convw + (L - 1) * 36864;   // (64,64,9)
        bn_prologue(stats + (L - 1) * 128, gammas + (L - 1) * 64,
                    betas + (L - 1) * 64, w + co * 576,
                    s_sc, s_sh, s_corr, tid, 0, 64);
        float u0,u1,u2,u3;
        conv_core<64,true>(bin + n * 64 * PS, w + co * 576,
                           s_sc, s_sh, r, c4, u0,u1,u2,u3);
        apply_corr(s_corr, r, c4, u0,u1,u2,u3);
        write_padded(bout + (n * 64 + co) * PS, r, c4, tid, u0,u1,u2,u3);
        stats_acc(stats + L * 128, co, tid, u0,u1,u2,u3);
        grid.sync();
    }

    // ---- regressor: 64 -> 12 from bufA (L4 output), ci-split x4 ----
    if (b < 192) {
        const int q     = b & 3;           // ci quarter
        const int idx   = b >> 2;          // 0..47
        const int nn    = idx / 12;
        const int cc    = idx - nn * 12;
        const int ci_lo = q << 4;
        bn_prologue(stats + 512, gammas + 256, betas + 256, regw + cc * 576,
                    s_sc, s_sh, s_corr, tid, ci_lo, ci_lo + 16);
        float u0,u1,u2,u3;
        conv_core<16,true>(bufA + nn * 64 * PS + ci_lo * PS,
                           regw + cc * 576 + ci_lo * 9,
                           s_sc + ci_lo, s_sh + ci_lo, r, c4, u0,u1,u2,u3);
        apply_corr(s_corr, r, c4, u0,u1,u2,u3);
        if (q == 0) {
            float bv = regb[cc];
            u0 += bv; u1 += bv; u2 += bv; u3 += bv;
        }
        float* op = xf + ((nn * 12 + cc) << 10) + (r << 5) + c4;
        atomicAdd(op + 0, u0); atomicAdd(op + 1, u1);
        atomicAdd(op + 2, u2); atomicAdd(op + 3, u3);
    }
}

// ---------------------------------------------------------------------------
// Hadamard attention (unchanged from round 3, which passed): one block per
// (t,i); att_w row read once, reused for 4 batch images; no max-subtraction
// (scores bounded well inside exp range); nontemporal stores for att.
// ---------------------------------------------------------------------------
__global__ __launch_bounds__(256) void attention_v2(
    const float* __restrict__ xf,     // (4,12,1024)
    const float* __restrict__ att_w,  // (12,1024,1024)
    float* __restrict__ out,          // (4,12,1024)
    float* __restrict__ att)          // (4,12,1024,1024)
{
    __shared__ __align__(16) float s_xf[4096];
    __shared__ float red[4][8];
    const int tid = threadIdx.x;
    const int t   = blockIdx.x >> 10;
    const int i   = blockIdx.x & 1023;
    const int w   = tid >> 6;

    const float4* xf4 = (const float4*)xf;
    float4* s4 = (float4*)s_xf;
    #pragma unroll
    for (int q = 0; q < 4; ++q) {
        int e  = (q << 8) + tid;
        int nn = e >> 8;
        int j4 = e & 255;
        s4[e] = xf4[((nn * 12 + t) << 8) + j4];
    }
    float4 wv = ((const float4*)att_w)[(((t << 10) + i) << 8) + tid];
    __syncthreads();

    float ev[4][4], ps[4], pd[4];
    #pragma unroll
    for (int nn = 0; nn < 4; ++nn) {
        float4 xv = ((const float4*)(s_xf + (nn << 10)))[tid];
        float e0 = __expf(wv.x * xv.x);
        float e1 = __expf(wv.y * xv.y);
        float e2 = __expf(wv.z * xv.z);
        float e3 = __expf(wv.w * xv.w);
        ps[nn] = (e0 + e1) + (e2 + e3);
        pd[nn] = fmaf(e0, xv.x, fmaf(e1, xv.y, fmaf(e2, xv.z, e3 * xv.w)));
        ev[nn][0] = e0; ev[nn][1] = e1; ev[nn][2] = e2; ev[nn][3] = e3;
    }
    #pragma unroll
    for (int off = 32; off; off >>= 1) {
        #pragma unroll
        for (int nn = 0; nn < 4; ++nn) {
            ps[nn] += __shfl_down(ps[nn], off);
            pd[nn] += __shfl_down(pd[nn], off);
        }
    }
    if ((tid & 63) == 0) {
        #pragma unroll
        for (int nn = 0; nn < 4; ++nn) {
            red[w][nn]     = ps[nn];
            red[w][4 + nn] = pd[nn];
        }
    }
    __syncthreads();

    #pragma unroll
    for (int nn = 0; nn < 4; ++nn) {
        float sum = (red[0][nn] + red[1][nn]) + (red[2][nn] + red[3][nn]);
        float dot = (red[0][4+nn] + red[1][4+nn]) + (red[2][4+nn] + red[3][4+nn]);
        float inv = 1.0f / sum;
        f32x4 av;
        av.x = ev[nn][0] * inv; av.y = ev[nn][1] * inv;
        av.z = ev[nn][2] * inv; av.w = ev[nn][3] * inv;
        f32x4* dst = (f32x4*)att + ((((nn * 12 + t) << 10) + i) << 8) + tid;
        __builtin_nontemporal_store(av, dst);
        if (tid == 0) out[((nn * 12 + t) << 10) + i] = dot * inv;
    }
}

extern "C" void kernel_launch(void* const* d_in, const int* in_sizes, int n_in,
                              void* d_out, int out_size, void* d_ws, size_t ws_size,
                              hipStream_t stream)
{
    const float* x      = (const float*)d_in[0];
    const float* conv0w = (const float*)d_in[1];
    const float* convw  = (const float*)d_in[2];
    const float* convb  = (const float*)d_in[3];  // unused: BN cancels bias
    const float* gammas = (const float*)d_in[4];
    const float* betas  = (const float*)d_in[5];
    const float* regw   = (const float*)d_in[6];
    const float* regb   = (const float*)d_in[7];
    const float* attw   = (const float*)d_in[8];
    (void)convb;

    float* out = (float*)d_out;                   // (4,12,32,32)
    float* att = out + 4 * 12 * 1024;             // (4,12,1024,1024)

    float* ws    = (float*)d_ws;
    float* stats = ws;                            // 640
    float* bufX  = stats + 640;                   // 48*PS
    float* bufA  = bufX + 48 * PS;                // 256*PS
    float* bufB  = bufA + 256 * PS;               // 256*PS
    float* xf    = bufB + 256 * PS;               // 49152

    void* kargs[] = {
        (void*)&x, (void*)&conv0w, (void*)&convw, (void*)&gammas,
        (void*)&betas, (void*)&regw, (void*)&regb,
        (void*)&bufX, (void*)&bufA, (void*)&bufB, (void*)&stats, (void*)&xf
    };
    (void)hipLaunchCooperativeKernel((void*)fused_conv, dim3(256), dim3(256),
                                     kargs, 0, stream);

    attention_v2<<<12288, 256, 0, stream>>>(xf, attw, out, att);
}